// Round 9
// baseline (1747.132 us; speedup 1.0000x reference)
//
#include <hip/hip_runtime.h>
#include <hip/hip_cooperative_groups.h>
#include <cmath>

namespace cg = cooperative_groups;

#define D_ 4096
#define H_ 32
#define HD_ 128
#define B_ 8
#define MAXSEQ_ 2048
#define AL_ 10
#define FF_ 11008
#define NBLK 256
#define TPB 1024
#define SCALE_ 0.08838834764831845f   // 1/sqrt(128)
#define EPS_ 1e-5f

// ---------------- generic GEMV core: one wave, NR rows, 64-float4 col slice ----------------
template<int NR, int ROWS, int CHUNK, int UNROLL>
__device__ __forceinline__ void gemv_core(
    const float4* __restrict__ W4, const float* __restrict__ xs /*[CHUNK][ROWS]*/,
    int i0, int N4, int j4, int r0, float* __restrict__ P, size_t pb, int N) {
  constexpr int RS = (ROWS + 3) & ~3;
  float4 acc[NR];
#pragma unroll
  for (int r = 0; r < NR; ++r) acc[r] = make_float4(0.f, 0.f, 0.f, 0.f);
  for (int iu = 0; iu < CHUNK; iu += UNROLL) {
    float4 w[UNROLL];
#pragma unroll
    for (int u = 0; u < UNROLL; ++u)
      w[u] = W4[(size_t)(i0 + iu + u) * N4 + j4];
#pragma unroll
    for (int u = 0; u < UNROLL; ++u) {
      float xr[RS];
#pragma unroll
      for (int q = 0; q < RS / 4; ++q)
        *(float4*)&xr[4 * q] = *(const float4*)&xs[(iu + u) * ROWS + 4 * q];
#pragma unroll
      for (int r = 0; r < NR; ++r) {
        float xv = xr[r0 + r];
        acc[r].x += xv * w[u].x; acc[r].y += xv * w[u].y;
        acc[r].z += xv * w[u].z; acc[r].w += xv * w[u].w;
      }
    }
  }
#pragma unroll
  for (int r = 0; r < NR; ++r)
    *(float4*)&P[(pb + r) * (size_t)N + (size_t)4 * j4] = acc[r];
}

// One GEMV tile for a 1024-thread block: 4 col-subslices x 4 row-groups = 16 waves.
// Tile covers [colbase .. colbase+256) float4 columns x CHUNK K-rows.
template<int ROWS, int RPG, int CHUNK, int UNROLL>
__device__ __forceinline__ void gemv_tile(
    const float* __restrict__ X, const float* __restrict__ W, float* __restrict__ P,
    int N, int K, int colbase, int kchunk, int zoff, float* smem, int tid) {
  int i0 = kchunk * CHUNK;
  for (int idx = tid; idx < ROWS * CHUNK; idx += TPB) {
    int r = idx / CHUNK, ii = idx - r * CHUNK;
    smem[ii * ROWS + r] = X[(size_t)r * K + i0 + ii];
  }
  __syncthreads();
  int wave = tid >> 6, lane = tid & 63;
  int colsub = wave & 3, rowg = wave >> 2;
  int r0 = rowg * RPG;
  int N4 = N >> 2;
  int j4 = colbase + colsub * 64 + lane;
  size_t pb = (size_t)zoff * ROWS + r0;
  constexpr int LAST = ROWS - 3 * RPG;
  if (j4 < N4) {
    if (r0 + RPG <= ROWS)
      gemv_core<RPG, ROWS, CHUNK, UNROLL>((const float4*)W, smem, i0, N4, j4, r0, P, pb, N);
    else if (LAST > 0)
      gemv_core<(LAST > 0 ? LAST : 1), ROWS, CHUNK, UNROLL>((const float4*)W, smem, i0, N4, j4, r0, P, pb, N);
  }
  __syncthreads();
}

// rmsnorm over one row of 4096 with 1024 threads
__device__ __forceinline__ void rmsnorm_phase(const float* __restrict__ in,
                                              const float* __restrict__ w,
                                              float* __restrict__ outp,
                                              int b, float* red, int tid) {
  const float* xr = in + (size_t)b * D_;
  float ss = 0.f;
#pragma unroll
  for (int q = 0; q < 4; ++q) { float v = xr[tid + q * TPB]; ss += v * v; }
  red[tid] = ss; __syncthreads();
  for (int s = 512; s; s >>= 1) { if (tid < s) red[tid] += red[tid + s]; __syncthreads(); }
  float r = rsqrtf(red[0] / (float)D_ + EPS_);
  __syncthreads();
  float* o = outp + (size_t)b * D_;
#pragma unroll
  for (int q = 0; q < 4; ++q) { int i = tid + q * TPB; o[i] = xr[i] * r * w[i]; }
}

// =========================== cooperative mega-kernel: 256 blocks x 1024 threads ===========================
__global__ __launch_bounds__(TPB, 1) void mega_k(
    const float* __restrict__ x, const float* __restrict__ adapter,
    const float* __restrict__ ck, const float* __restrict__ cv,
    const float* __restrict__ fc, const float* __restrict__ fs,
    const float* __restrict__ wq, const float* __restrict__ wk,
    const float* __restrict__ wv, const float* __restrict__ wo,
    const float* __restrict__ gate, const float* __restrict__ anw,
    const float* __restrict__ fnw, const float* __restrict__ w1,
    const float* __restrict__ w2, const float* __restrict__ w3,
    float* __restrict__ out, float* __restrict__ ws) {
  cg::grid_group grid = cg::this_grid();
  __shared__ float smem[4672];                 // 18.7 KB union
  int blk = blockIdx.x, tid = threadIdx.x;

  float* xa      = ws;                         // 18*4096
  float* qp      = xa + 18 * D_;               // rows 0..7 = q (roped)
  float* kp      = qp + 18 * D_;               // rows 0..7 = new k (roped), 8..17 = ak
  float* vp      = kp + 18 * D_;               // rows 0..7 = new v, 8..17 = av
  float* attn    = vp + 18 * D_;               // 8*4096
  float* hbuf    = attn + 8 * D_;              // 8*4096
  float* hn      = hbuf + 8 * D_;              // 8*4096
  float* gb      = hn + 8 * D_;                // 8*11008
  float* scratch = gb + 8 * FF_;               // max: attn partials 8*128*32*132 = 17.3MB

  // ---------- Phase A: xa = [rmsnorm(x); adapter] ----------
  if (blk < 8) {
    rmsnorm_phase(x, anw, xa, blk, smem, tid);
  } else if (blk < 18) {
    int r = blk - 8;
    const float4* src = (const float4*)(adapter + (size_t)r * D_);
    float4* dst = (float4*)(xa + (size_t)(8 + r) * D_);
    dst[tid] = src[tid];
  }
  grid.sync();

  // ---------- Phase B: QKV gemv — 192 tiles (4 col x 16 k x 3 mats), 1/block ----------
  if (blk < 192) {
    int ct = blk & 3, kc = (blk >> 2) & 15, z = blk >> 6;
    const float* W = (z == 0) ? wq : (z == 1) ? wk : wv;
    gemv_tile<18, 5, 256, 4>(xa, W, scratch, D_, D_, ct * 256, kc, z * 16 + kc, smem, tid);
  }
  grid.sync();

  // ---------- Phase C: reduce 16 chunks + RoPE q,k rows 0..7 (54 blocks) ----------
  if (blk < 54) {
    int gi = blk * TPB + tid;                  // < 55296 = 3*18432
    int z = gi / 18432, i4 = gi - z * 18432;
    const float4* P4 = (const float4*)scratch;
    size_t base = (size_t)z * 16 * 18432 + i4;
    float4 s = make_float4(0.f, 0.f, 0.f, 0.f);
#pragma unroll
    for (int c = 0; c < 16; ++c) {
      float4 v = P4[base + (size_t)c * 18432];
      s.x += v.x; s.y += v.y; s.z += v.z; s.w += v.w;
    }
    int row = i4 >> 10;
    if (z < 2 && row < 8) {
      int c0 = (i4 & 1023) << 2;
      int p0 = (c0 & 127) >> 1;
      float ca = fc[p0], sa = fs[p0], cb = fc[p0 + 1], sb = fs[p0 + 1];
      float4 r;
      r.x = s.x * ca - s.y * sa; r.y = s.x * sa + s.y * ca;
      r.z = s.z * cb - s.w * sb; r.w = s.z * sb + s.w * cb;
      s = r;
    }
    float4* Y = (float4*)(z == 0 ? qp : z == 1 ? kp : vp);
    Y[i4] = s;
  }
  grid.sync();

  // ---------- Phase D: flash-decode. block = (b, 64-pos chunk); wave = 16 pos x 8 heads ----------
  {
    int b = blk >> 5, c = blk & 31;
    int wave = tid >> 6, lane = tid & 63;
    int psub = wave >> 2, hg = wave & 3;
    int hl = lane >> 3, h = hg * 8 + hl;
    int d0 = (lane & 7) << 4;
    const float4* q4 = (const float4*)&qp[(size_t)b * D_ + h * HD_ + d0];
    float4 q0 = q4[0], q1 = q4[1], q2 = q4[2], q3 = q4[3];
    int t0 = c * 64 + psub * 16;
    size_t base = ((size_t)(b * MAXSEQ_ + t0)) * D_ + (size_t)h * HD_ + d0;
    float m = -INFINITY, l = 0.f;
    float4 o0 = make_float4(0.f,0.f,0.f,0.f), o1 = o0, o2 = o0, o3 = o0;
#pragma unroll 4
    for (int i = 0; i < 16; ++i) {
      size_t off = base + (size_t)i * D_;
      const float4* kp4 = (const float4*)&ck[off];
      float4 k0 = kp4[0], k1 = kp4[1], k2 = kp4[2], k3 = kp4[3];
      float s = q0.x*k0.x + q0.y*k0.y + q0.z*k0.z + q0.w*k0.w
              + q1.x*k1.x + q1.y*k1.y + q1.z*k1.z + q1.w*k1.w
              + q2.x*k2.x + q2.y*k2.y + q2.z*k2.z + q2.w*k2.w
              + q3.x*k3.x + q3.y*k3.y + q3.z*k3.z + q3.w*k3.w;
      s += __shfl_xor(s, 1); s += __shfl_xor(s, 2); s += __shfl_xor(s, 4);
      s *= SCALE_;
      if (t0 + i == MAXSEQ_ - 1) s = -1e30f;   // new token folded in combine
      float mn = fmaxf(m, s);
      float r = __expf(m - mn), p = __expf(s - mn);
      const float4* vp4 = (const float4*)&cv[off];
      float4 v0 = vp4[0], v1 = vp4[1], v2 = vp4[2], v3 = vp4[3];
      o0.x = o0.x*r + p*v0.x; o0.y = o0.y*r + p*v0.y; o0.z = o0.z*r + p*v0.z; o0.w = o0.w*r + p*v0.w;
      o1.x = o1.x*r + p*v1.x; o1.y = o1.y*r + p*v1.y; o1.z = o1.z*r + p*v1.z; o1.w = o1.w*r + p*v1.w;
      o2.x = o2.x*r + p*v2.x; o2.y = o2.y*r + p*v2.y; o2.z = o2.z*r + p*v2.z; o2.w = o2.w*r + p*v2.w;
      o3.x = o3.x*r + p*v3.x; o3.y = o3.y*r + p*v3.y; o3.z = o3.z*r + p*v3.z; o3.w = o3.w*r + p*v3.w;
      l = l * r + p; m = mn;
    }
    int chunk128 = c * 4 + psub;
    float* po = &scratch[(((size_t)b * 128 + chunk128) * H_ + h) * 132];
    if ((lane & 7) == 0) { po[0] = m; po[1] = l; }
    float4* po4 = (float4*)&po[4 + d0];
    po4[0] = o0; po4[1] = o1; po4[2] = o2; po4[3] = o3;
  }
  grid.sync();

  // ---------- Phase E: combine 128 partials + new token + adapter; 8 (b,h) pairs/block ----------
  if (blk < 32) {
    int pr = tid >> 7, t2 = tid & 127;
    int bh = blk * 8 + pr;
    int h = bh & 31, b = bh >> 5;
    int w2i = (tid >> 6) & 1, lane = tid & 63;
    const size_t cs = (size_t)H_ * 132;
    const float* pb = &scratch[((size_t)b * 128 * H_ + h) * 132];
    float* sm = smem + pr * 288;               // 128
    float* sl = sm + 128;                       // 128
    float* s2 = sl + 128;                       // 24
    sm[t2] = pb[cs * t2];
    sl[t2] = pb[cs * t2 + 1];
    __syncthreads();
    float M = -INFINITY;
    for (int c2 = 0; c2 < 128; ++c2) M = fmaxf(M, sm[c2]);
    float L = 0.f, O = 0.f;
#pragma unroll 4
    for (int c2 = 0; c2 < 128; ++c2) {
      float e = __expf(sm[c2] - M);
      L += e * sl[c2];
      O += e * pb[cs * c2 + 4 + t2];
    }
    size_t qi = (size_t)b * D_ + h * HD_ + t2;
    float qd = qp[qi];
    {
      float prd = qd * kp[qi];
      prd += __shfl_xor(prd, 32); prd += __shfl_xor(prd, 16); prd += __shfl_xor(prd, 8);
      prd += __shfl_xor(prd, 4);  prd += __shfl_xor(prd, 2);  prd += __shfl_xor(prd, 1);
      if (lane == 0) s2[w2i * 12 + 10] = prd;
    }
    for (int j = 0; j < 10; ++j) {
      float prd = qd * kp[(size_t)(8 + j) * D_ + h * HD_ + t2];
      prd += __shfl_xor(prd, 32); prd += __shfl_xor(prd, 16); prd += __shfl_xor(prd, 8);
      prd += __shfl_xor(prd, 4);  prd += __shfl_xor(prd, 2);  prd += __shfl_xor(prd, 1);
      if (lane == 0) s2[w2i * 12 + j] = prd;
    }
    __syncthreads();
    float s_new = (s2[10] + s2[12 + 10]) * SCALE_;
    float M2 = fmaxf(M, s_new);
    float eM = __expf(M - M2), eN = __expf(s_new - M2);
    L = L * eM + eN;
    O = O * eM + eN * vp[qi];
    float main_out = O / L;
    float ma = -INFINITY, sa[10];
    for (int j = 0; j < 10; ++j) { sa[j] = (s2[j] + s2[12 + j]) * SCALE_; ma = fmaxf(ma, sa[j]); }
    float la = 0.f, pj[10];
    for (int j = 0; j < 10; ++j) { pj[j] = __expf(sa[j] - ma); la += pj[j]; }
    float ao = 0.f;
    for (int j = 0; j < 10; ++j) ao += pj[j] * vp[(size_t)(8 + j) * D_ + h * HD_ + t2];
    ao /= la;
    float g = tanhf(gate[h]);
    attn[qi] = main_out + g * ao;
  }
  grid.sync();

  // ---------- Phase F: wo gemv — 256 tiles (4 col x 64 k), 1/block ----------
  {
    int ct = blk & 3, kc = blk >> 2;
    gemv_tile<8, 2, 64, 8>(attn, wo, scratch, D_, D_, ct * 256, kc, kc, smem, tid);
  }
  grid.sync();

  // ---------- Phase G: h = x + sum 64 partials (8 blocks) ----------
  if (blk < 8) {
    int i4 = blk * TPB + tid;                  // < 8192
    const float4* P4 = (const float4*)scratch;
    float4 s = ((const float4*)x)[i4];
    for (int c = 0; c < 64; ++c) {
      float4 v = P4[(size_t)c * 8192 + i4];
      s.x += v.x; s.y += v.y; s.z += v.z; s.w += v.w;
    }
    ((float4*)hbuf)[i4] = s;
  }
  grid.sync();

  // ---------- Phase H: hn = rmsnorm(h) ----------
  if (blk < 8) rmsnorm_phase(hbuf, fnw, hn, blk, smem, tid);
  grid.sync();

  // ---------- Phase I: FFN w1/w3 gemv — 352 tiles (11 col x 16 k x 2 mats) ----------
  for (int vb = blk; vb < 352; vb += NBLK) {
    int ct = vb % 11, r = vb / 11;
    int kc = r & 15, z = r >> 4;
    const float* W = z ? w3 : w1;
    gemv_tile<8, 2, 256, 8>(hn, W, scratch, FF_, D_, ct * 256, kc, z * 16 + kc, smem, tid);
  }
  grid.sync();

  // ---------- Phase J: gb = silu(sum z0) * (sum z1) (22 blocks) ----------
  if (blk < 22) {
    int i4 = blk * TPB + tid;
    if (i4 < 22016) {
      const float4* P4 = (const float4*)scratch;
      float4 a = make_float4(0.f, 0.f, 0.f, 0.f);
      float4 b = make_float4(0.f, 0.f, 0.f, 0.f);
#pragma unroll
      for (int c = 0; c < 16; ++c) {
        float4 u = P4[(size_t)c * 22016 + i4];
        float4 v = P4[(size_t)(16 + c) * 22016 + i4];
        a.x += u.x; a.y += u.y; a.z += u.z; a.w += u.w;
        b.x += v.x; b.y += v.y; b.z += v.z; b.w += v.w;
      }
      float4 o;
      o.x = (a.x / (1.f + __expf(-a.x))) * b.x;
      o.y = (a.y / (1.f + __expf(-a.y))) * b.y;
      o.z = (a.z / (1.f + __expf(-a.z))) * b.z;
      o.w = (a.w / (1.f + __expf(-a.w))) * b.w;
      ((float4*)gb)[i4] = o;
    }
  }
  grid.sync();

  // ---------- Phase K: w2 gemv — 256 tiles (4 col x 64 k), 1/block ----------
  {
    int ct = blk & 3, kc = blk >> 2;
    gemv_tile<8, 2, 172, 4>(gb, w2, scratch, D_, FF_, ct * 256, kc, kc, smem, tid);
  }
  grid.sync();

  // ---------- Phase L: out = h + sum 64 partials (8 blocks) ----------
  if (blk < 8) {
    int i4 = blk * TPB + tid;
    const float4* P4 = (const float4*)scratch;
    float4 s = ((const float4*)hbuf)[i4];
    for (int c = 0; c < 64; ++c) {
      float4 v = P4[(size_t)c * 8192 + i4];
      s.x += v.x; s.y += v.y; s.z += v.z; s.w += v.w;
    }
    ((float4*)out)[i4] = s;
  }
}

// =========================== fallback path (R5 multi-kernel, known-good) ===========================
template<int NR, int ROWS, int CHUNK, int UNROLL>
__device__ __forceinline__ void gemv_core_fb(
    const float4* __restrict__ W4, const float (*xs)[ROWS],
    int i0, int N4, int j4, int r0, float* __restrict__ P, size_t pb, int N) {
  float4 acc[NR];
#pragma unroll
  for (int r = 0; r < NR; ++r) acc[r] = make_float4(0.f, 0.f, 0.f, 0.f);
  for (int iu = 0; iu < CHUNK; iu += UNROLL) {
    float4 w[UNROLL];
#pragma unroll
    for (int u = 0; u < UNROLL; ++u)
      w[u] = W4[(size_t)(i0 + iu + u) * N4 + j4];
#pragma unroll
    for (int u = 0; u < UNROLL; ++u) {
#pragma unroll
      for (int r = 0; r < NR; ++r) {
        float xv = xs[iu + u][r0 + r];
        acc[r].x += xv * w[u].x; acc[r].y += xv * w[u].y;
        acc[r].z += xv * w[u].z; acc[r].w += xv * w[u].w;
      }
    }
  }
#pragma unroll
  for (int r = 0; r < NR; ++r)
    *(float4*)&P[(pb + r) * (size_t)N + (size_t)4 * j4] = acc[r];
}

__global__ __launch_bounds__(256) void norm_adapter_k(const float* __restrict__ x,
                                                      const float* __restrict__ w,
                                                      const float* __restrict__ adapter,
                                                      float* __restrict__ xa) {
  int b = blockIdx.x, tid = threadIdx.x;
  if (b < 8) {
    const float* xr = x + (size_t)b * D_;
    float ss = 0.f;
    for (int i = tid; i < D_; i += 256) { float v = xr[i]; ss += v * v; }
    __shared__ float red[256];
    red[tid] = ss; __syncthreads();
    for (int s = 128; s; s >>= 1) { if (tid < s) red[tid] += red[tid + s]; __syncthreads(); }
    float r = rsqrtf(red[0] / (float)D_ + EPS_);
    float* o = xa + (size_t)b * D_;
    for (int i = tid; i < D_; i += 256) o[i] = xr[i] * r * w[i];
  } else {
    int r = b - 8;
    const float4* src = (const float4*)(adapter + (size_t)r * D_);
    float4* dst = (float4*)(xa + (size_t)(8 + r) * D_);
    for (int i = tid; i < D_ / 4; i += 256) dst[i] = src[i];
  }
}

__global__ __launch_bounds__(256) void rmsnorm_k(const float* __restrict__ in,
                                                 const float* __restrict__ w,
                                                 float* __restrict__ out) {
  int b = blockIdx.x, tid = threadIdx.x;
  const float* x = in + (size_t)b * D_;
  float ss = 0.f;
  for (int i = tid; i < D_; i += 256) { float v = x[i]; ss += v * v; }
  __shared__ float red[256];
  red[tid] = ss; __syncthreads();
  for (int s = 128; s; s >>= 1) { if (tid < s) red[tid] += red[tid + s]; __syncthreads(); }
  float r = rsqrtf(red[0] / (float)D_ + EPS_);
  float* o = out + (size_t)b * D_;
  for (int i = tid; i < D_; i += 256) o[i] = x[i] * r * w[i];
}

template<int ROWS, int RPG, int CHUNK, int UNROLL>
__global__ __launch_bounds__(256, 1) void gemv_rs(
    const float* __restrict__ X,
    const float* __restrict__ Wa, const float* __restrict__ Wb, const float* __restrict__ Wc,
    float* __restrict__ P, int N, int K) {
  const float* W = (blockIdx.z == 0) ? Wa : (blockIdx.z == 1) ? Wb : Wc;
  __shared__ float xs[CHUNK][ROWS];
  int tid = threadIdx.x;
  int i0 = blockIdx.y * CHUNK;
  for (int idx = tid; idx < ROWS * CHUNK; idx += 256) {
    int r = idx / CHUNK, ii = idx - r * CHUNK;
    xs[ii][r] = X[(size_t)r * K + i0 + ii];
  }
  __syncthreads();
  int wave = tid >> 6, lane = tid & 63;
  int r0 = wave * RPG;
  int N4 = N >> 2;
  int j4 = blockIdx.x * 64 + lane;
  const float4* W4 = (const float4*)W;
  size_t pb = ((size_t)blockIdx.z * gridDim.y + blockIdx.y) * ROWS + r0;
  constexpr int LAST = ROWS - 3 * RPG;
  if (r0 + RPG <= ROWS)
    gemv_core_fb<RPG, ROWS, CHUNK, UNROLL>(W4, xs, i0, N4, j4, r0, P, pb, N);
  else if (LAST > 0)
    gemv_core_fb<(LAST > 0 ? LAST : 1), ROWS, CHUNK, UNROLL>(W4, xs, i0, N4, j4, r0, P, pb, N);
}

__global__ __launch_bounds__(256) void reduce3_rope_k(
    const float* __restrict__ P, const float* __restrict__ fc, const float* __restrict__ fs,
    float* __restrict__ Ya, float* __restrict__ Yb, float* __restrict__ Yc) {
  int z = blockIdx.z;
  int i4 = blockIdx.x * 256 + threadIdx.x;
  const float4* P4 = (const float4*)P;
  size_t base = (size_t)z * 16 * 18432 + i4;
  float4 s = make_float4(0.f, 0.f, 0.f, 0.f);
#pragma unroll
  for (int c = 0; c < 16; ++c) {
    float4 v = P4[base + (size_t)c * 18432];
    s.x += v.x; s.y += v.y; s.z += v.z; s.w += v.w;
  }
  int row = i4 >> 10;
  if (z < 2 && row < 8) {
    int c0 = (i4 & 1023) << 2;
    int p0 = (c0 & 127) >> 1;
    float ca = fc[p0], sa = fs[p0], cb = fc[p0 + 1], sb = fs[p0 + 1];
    float4 r;
    r.x = s.x * ca - s.y * sa; r.y = s.x * sa + s.y * ca;
    r.z = s.z * cb - s.w * sb; r.w = s.z * sb + s.w * cb;
    s = r;
  }
  float4* Y = (float4*)(z == 0 ? Ya : z == 1 ? Yb : Yc);
  Y[i4] = s;
}

__global__ __launch_bounds__(256) void reduceB_k(const float* __restrict__ P,
                                                 const float* __restrict__ base,
                                                 float* __restrict__ Y, int n4, int nc) {
  int i4 = blockIdx.x * 256 + threadIdx.x;
  if (i4 >= n4) return;
  const float4* P4 = (const float4*)P;
  float4 s = ((const float4*)base)[i4];
  for (int c = 0; c < nc; ++c) {
    float4 v = P4[(size_t)c * n4 + i4];
    s.x += v.x; s.y += v.y; s.z += v.z; s.w += v.w;
  }
  ((float4*)Y)[i4] = s;
}

__global__ __launch_bounds__(256) void reduce_silu_k(const float* __restrict__ P,
                                                     float* __restrict__ gb) {
  int i4 = blockIdx.x * 256 + threadIdx.x;
  const float4* P4 = (const float4*)P;
  float4 a = make_float4(0.f, 0.f, 0.f, 0.f);
  float4 b = make_float4(0.f, 0.f, 0.f, 0.f);
#pragma unroll
  for (int c = 0; c < 8; ++c) {
    float4 u = P4[(size_t)c * 22016 + i4];
    float4 v = P4[(size_t)(8 + c) * 22016 + i4];
    a.x += u.x; a.y += u.y; a.z += u.z; a.w += u.w;
    b.x += v.x; b.y += v.y; b.z += v.z; b.w += v.w;
  }
  float4 o;
  o.x = (a.x / (1.f + __expf(-a.x))) * b.x;
  o.y = (a.y / (1.f + __expf(-a.y))) * b.y;
  o.z = (a.z / (1.f + __expf(-a.z))) * b.z;
  o.w = (a.w / (1.f + __expf(-a.w))) * b.w;
  ((float4*)gb)[i4] = o;
}

__global__ __launch_bounds__(256) void attn_partial_fb(
    const float* __restrict__ qp, const float* __restrict__ ck,
    const float* __restrict__ cv, float* __restrict__ part) {
  int idx = blockIdx.x;
  int c = idx & 7, bh = idx >> 3;
  int h = bh & 31, b = bh >> 5;
  int tid = threadIdx.x, wave = tid >> 6, lane = tid & 63;
  int half = lane >> 5, l32 = lane & 31;
  int t0 = c * 256 + wave * 64;
  const float4 qv = *(const float4*)&qp[(size_t)b * D_ + h * HD_ + 4 * l32];
  const size_t kvbase = ((size_t)b * MAXSEQ_) * (H_ * HD_) + (size_t)h * HD_ + 4 * l32;
  float m = -INFINITY, l = 0.f;
  float4 o = make_float4(0.f, 0.f, 0.f, 0.f);
#pragma unroll 4
  for (int i = 0; i < 32; ++i) {
    int t = t0 + 2 * i + half;
    size_t off = kvbase + (size_t)t * (H_ * HD_);
    float4 kv = *(const float4*)&ck[off];
    float s = qv.x * kv.x + qv.y * kv.y + qv.z * kv.z + qv.w * kv.w;
    s += __shfl_xor(s, 16); s += __shfl_xor(s, 8);
    s += __shfl_xor(s, 4);  s += __shfl_xor(s, 2); s += __shfl_xor(s, 1);
    s *= SCALE_;
    if (t == MAXSEQ_ - 1) s = -1e30f;
    float mn = fmaxf(m, s);
    float r = __expf(m - mn), p = __expf(s - mn);
    float4 vv = *(const float4*)&cv[off];
    o.x = o.x * r + p * vv.x; o.y = o.y * r + p * vv.y;
    o.z = o.z * r + p * vv.z; o.w = o.w * r + p * vv.w;
    l = l * r + p; m = mn;
  }
  float mo = __shfl_xor(m, 32);
  float M = fmaxf(m, mo);
  float e = __expf(m - M);
  o.x *= e; o.y *= e; o.z *= e; o.w *= e; l *= e;
  o.x += __shfl_xor(o.x, 32); o.y += __shfl_xor(o.y, 32);
  o.z += __shfl_xor(o.z, 32); o.w += __shfl_xor(o.w, 32);
  l += __shfl_xor(l, 32);
  float* po = &part[((size_t)idx * 4 + wave) * 132];
  if (lane == 0) { po[0] = M; po[1] = l; }
  if (half == 0) *(float4*)&po[4 + 4 * l32] = o;
}

__global__ __launch_bounds__(128) void attn_combine_fb(
    const float* __restrict__ part, const float* __restrict__ qp,
    const float* __restrict__ kvk, const float* __restrict__ kvv,
    const float* __restrict__ gate, float* __restrict__ attn) {
  int bh = blockIdx.x;
  int h = bh & 31, b = bh >> 5;
  int tid = threadIdx.x;
  const float* pb = &part[(size_t)bh * 32 * 132];
  __shared__ float sm[32], sl[32];
  if (tid < 32) { sm[tid] = pb[tid * 132]; sl[tid] = pb[tid * 132 + 1]; }
  __syncthreads();
  float M = -INFINITY;
  for (int c = 0; c < 32; ++c) M = fmaxf(M, sm[c]);
  float L = 0.f, O = 0.f;
  for (int c = 0; c < 32; ++c) {
    float e = __expf(sm[c] - M);
    L += e * sl[c];
    O += e * pb[c * 132 + 4 + tid];
  }
  size_t qi = (size_t)b * D_ + h * HD_ + tid;
  float qd = qp[qi];
  __shared__ float red[128];
  __shared__ float sa[10];
  red[tid] = qd * kvk[qi]; __syncthreads();
  for (int s = 64; s; s >>= 1) { if (tid < s) red[tid] += red[tid + s]; __syncthreads(); }
  float s_new = red[0] * SCALE_;
  __syncthreads();
  float M2 = fmaxf(M, s_new);
  float eM = __expf(M - M2), eN = __expf(s_new - M2);
  L = L * eM + eN;
  O = O * eM + eN * kvv[qi];
  float main_out = O / L;
  for (int j = 0; j < 10; ++j) {
    float prod = qd * kvk[(size_t)(8 + j) * D_ + h * HD_ + tid];
    red[tid] = prod; __syncthreads();
    for (int s = 64; s; s >>= 1) { if (tid < s) red[tid] += red[tid + s]; __syncthreads(); }
    if (tid == 0) sa[j] = red[0] * SCALE_;
    __syncthreads();
  }
  float ma = -INFINITY;
  for (int j = 0; j < 10; ++j) ma = fmaxf(ma, sa[j]);
  float la = 0.f, pj[10];
  for (int j = 0; j < 10; ++j) { pj[j] = __expf(sa[j] - ma); la += pj[j]; }
  float ao = 0.f;
  for (int j = 0; j < 10; ++j) ao += pj[j] * kvv[(size_t)(8 + j) * D_ + h * HD_ + tid];
  ao /= la;
  float g = tanhf(gate[h]);
  attn[qi] = main_out + g * ao;
}

extern "C" void kernel_launch(void* const* d_in, const int* in_sizes, int n_in,
                              void* d_out, int out_size, void* d_ws, size_t ws_size,
                              hipStream_t stream) {
  (void)in_sizes; (void)n_in; (void)out_size; (void)ws_size;
  const float* x       = (const float*)d_in[0];
  const float* adapter = (const float*)d_in[1];
  const float* ck      = (const float*)d_in[2];
  const float* cv      = (const float*)d_in[3];
  const float* fc      = (const float*)d_in[4];
  const float* fs      = (const float*)d_in[5];
  const float* wq      = (const float*)d_in[6];
  const float* wk      = (const float*)d_in[7];
  const float* wv      = (const float*)d_in[8];
  const float* wo      = (const float*)d_in[9];
  const float* gate    = (const float*)d_in[10];
  const float* anw     = (const float*)d_in[11];
  const float* fnw     = (const float*)d_in[12];
  const float* w1      = (const float*)d_in[13];
  const float* w2      = (const float*)d_in[14];
  const float* w3      = (const float*)d_in[15];
  float* out = (float*)d_out;
  float* ws  = (float*)d_ws;

  void* args[] = {
    (void*)&x, (void*)&adapter, (void*)&ck, (void*)&cv, (void*)&fc, (void*)&fs,
    (void*)&wq, (void*)&wk, (void*)&wv, (void*)&wo, (void*)&gate, (void*)&anw,
    (void*)&fnw, (void*)&w1, (void*)&w2, (void*)&w3, (void*)&out, (void*)&ws
  };
  hipError_t err = hipLaunchCooperativeKernel((void*)mega_k, dim3(NBLK), dim3(TPB), args, 0, stream);
  if (err != hipSuccess) {
    // -------- deterministic fallback: known-good R5 multi-kernel path --------
    float* xa      = ws;
    float* qp      = xa + 18 * D_;
    float* kp      = qp + 18 * D_;
    float* vp      = kp + 18 * D_;
    float* attn    = vp + 18 * D_;
    float* hbuf    = attn + 8 * D_;
    float* hn      = hbuf + 8 * D_;
    float* gb      = hn + 8 * D_;
    float* scratch = gb + 8 * FF_;

    norm_adapter_k<<<18, 256, 0, stream>>>(x, anw, adapter, xa);
    gemv_rs<18, 5, 256, 16><<<dim3(16, 16, 3), 256, 0, stream>>>(xa, wq, wk, wv, scratch, D_, D_);
    reduce3_rope_k<<<dim3(72, 1, 3), 256, 0, stream>>>(scratch, fc, fs, qp, kp, vp);
    attn_partial_fb<<<2048, 256, 0, stream>>>(qp, ck, cv, scratch);
    attn_combine_fb<<<256, 128, 0, stream>>>(scratch, qp, kp, vp, gate, attn);
    gemv_rs<8, 2, 128, 16><<<dim3(16, 32, 1), 256, 0, stream>>>(attn, wo, wo, wo, scratch, D_, D_);
    reduceB_k<<<32, 256, 0, stream>>>(scratch, x, hbuf, 8192, 32);
    rmsnorm_k<<<8, 256, 0, stream>>>(hbuf, fnw, hn);
    gemv_rs<8, 2, 512, 16><<<dim3(43, 8, 2), 256, 0, stream>>>(hn, w1, w3, w3, scratch, FF_, D_);
    reduce_silu_k<<<86, 256, 0, stream>>>(scratch, gb);
    gemv_rs<8, 2, 344, 8><<<dim3(16, 32, 1), 256, 0, stream>>>(gb, w2, w2, w2, scratch, D_, FF_);
    reduceB_k<<<32, 256, 0, stream>>>(scratch, hbuf, out, 8192, 32);
  }
}

// Round 10
// 452.496 us; speedup vs baseline: 3.8611x; 3.8611x over previous
//
#include <hip/hip_runtime.h>
#include <cmath>

#define D_ 4096
#define H_ 32
#define HD_ 128
#define B_ 8
#define MAXSEQ_ 2048
#define AL_ 10
#define FF_ 11008
#define SCALE_ 0.08838834764831845f   // 1/sqrt(128)
#define EPS_ 1e-5f
#define PSTRIDE 160                   // attn partial record stride (floats); o[] at +32 (64B aligned)

// ---------- fused: rmsnorm(x) -> xa rows 0..7 ; adapter copy -> xa rows 8..17 ----------
__global__ __launch_bounds__(256) void norm_adapter_k(const float* __restrict__ x,
                                                      const float* __restrict__ w,
                                                      const float* __restrict__ adapter,
                                                      float* __restrict__ xa) {
  int b = blockIdx.x, tid = threadIdx.x;
  if (b < 8) {
    const float* xr = x + (size_t)b * D_;
    float ss = 0.f;
    for (int i = tid; i < D_; i += 256) { float v = xr[i]; ss += v * v; }
    __shared__ float red[256];
    red[tid] = ss; __syncthreads();
    for (int s = 128; s; s >>= 1) { if (tid < s) red[tid] += red[tid + s]; __syncthreads(); }
    float r = rsqrtf(red[0] / (float)D_ + EPS_);
    float* o = xa + (size_t)b * D_;
    for (int i = tid; i < D_; i += 256) o[i] = xr[i] * r * w[i];
  } else {
    int r = b - 8;
    const float4* src = (const float4*)(adapter + (size_t)r * D_);
    float4* dst = (float4*)(xa + (size_t)(8 + r) * D_);
    for (int i = tid; i < D_ / 4; i += 256) dst[i] = src[i];
  }
}

// ------------- row-split split-K GEMV: 4 waves/block, each wave owns <=NR rows -------------
template<int NR, int ROWS, int CHUNK, int UNROLL>
__device__ __forceinline__ void gemv_core(
    const float4* __restrict__ W4, const float (*xs)[ROWS],
    int i0, int N4, int j4, int r0, float* __restrict__ P, size_t pb, int N) {
  float4 acc[NR];
#pragma unroll
  for (int r = 0; r < NR; ++r) acc[r] = make_float4(0.f, 0.f, 0.f, 0.f);
  for (int iu = 0; iu < CHUNK; iu += UNROLL) {
    float4 w[UNROLL];
#pragma unroll
    for (int u = 0; u < UNROLL; ++u)
      w[u] = W4[(size_t)(i0 + iu + u) * N4 + j4];
#pragma unroll
    for (int u = 0; u < UNROLL; ++u) {
#pragma unroll
      for (int r = 0; r < NR; ++r) {
        float xv = xs[iu + u][r0 + r];
        acc[r].x += xv * w[u].x; acc[r].y += xv * w[u].y;
        acc[r].z += xv * w[u].z; acc[r].w += xv * w[u].w;
      }
    }
  }
#pragma unroll
  for (int r = 0; r < NR; ++r)
    *(float4*)&P[(pb + r) * (size_t)N + (size_t)4 * j4] = acc[r];
}

// grid = (N4/64, K/CHUNK, nmat); block = 256 (4 waves).
template<int ROWS, int RPG, int CHUNK, int UNROLL>
__global__ __launch_bounds__(256, 1) void gemv_rs(
    const float* __restrict__ X,
    const float* __restrict__ Wa, const float* __restrict__ Wb, const float* __restrict__ Wc,
    float* __restrict__ P, int N, int K) {
  const float* W = (blockIdx.z == 0) ? Wa : (blockIdx.z == 1) ? Wb : Wc;
  __shared__ float xs[CHUNK][ROWS];
  int tid = threadIdx.x;
  int i0 = blockIdx.y * CHUNK;
  for (int idx = tid; idx < ROWS * CHUNK; idx += 256) {
    int r = idx / CHUNK, ii = idx - r * CHUNK;
    xs[ii][r] = X[(size_t)r * K + i0 + ii];
  }
  __syncthreads();
  int wave = tid >> 6, lane = tid & 63;
  int r0 = wave * RPG;
  int N4 = N >> 2;
  int j4 = blockIdx.x * 64 + lane;
  const float4* W4 = (const float4*)W;
  size_t pb = ((size_t)blockIdx.z * gridDim.y + blockIdx.y) * ROWS + r0;
  constexpr int LAST = ROWS - 3 * RPG;
  if (r0 + RPG <= ROWS)
    gemv_core<RPG, ROWS, CHUNK, UNROLL>(W4, xs, i0, N4, j4, r0, P, pb, N);
  else if (LAST > 0)
    gemv_core<(LAST > 0 ? LAST : 1), ROWS, CHUNK, UNROLL>(W4, xs, i0, N4, j4, r0, P, pb, N);
}

// ------- QKV reduction over nc chunks + fused RoPE on q,k rows 0..7 -------
// P: [z(3)][chunk(nc)][row(18)][4096]
__global__ __launch_bounds__(256) void reduce3_rope_k(
    const float* __restrict__ P, const float* __restrict__ fc, const float* __restrict__ fs,
    float* __restrict__ Ya, float* __restrict__ Yb, float* __restrict__ Yc, int nc) {
  int z = blockIdx.z;
  int i4 = blockIdx.x * 256 + threadIdx.x;      // 18432 float4 per z
  const float4* P4 = (const float4*)P;
  size_t base = (size_t)z * nc * 18432 + i4;
  float4 s = make_float4(0.f, 0.f, 0.f, 0.f);
  for (int c = 0; c < nc; ++c) {
    float4 v = P4[base + (size_t)c * 18432];
    s.x += v.x; s.y += v.y; s.z += v.z; s.w += v.w;
  }
  int row = i4 >> 10;
  if (z < 2 && row < 8) {
    int c0 = (i4 & 1023) << 2;
    int p0 = (c0 & 127) >> 1;
    float ca = fc[p0], sa = fs[p0], cb = fc[p0 + 1], sb = fs[p0 + 1];
    float4 r;
    r.x = s.x * ca - s.y * sa; r.y = s.x * sa + s.y * ca;
    r.z = s.z * cb - s.w * sb; r.w = s.z * sb + s.w * cb;
    s = r;
  }
  float4* Y = (float4*)(z == 0 ? Ya : z == 1 ? Yb : Yc);
  Y[i4] = s;
}

// ------- reduction with residual base: Y = base + sum_c P[c] -------
__global__ __launch_bounds__(256) void reduceB_k(const float* __restrict__ P,
                                                 const float* __restrict__ base,
                                                 float* __restrict__ Y, int n4, int nc) {
  int i4 = blockIdx.x * 256 + threadIdx.x;
  if (i4 >= n4) return;
  const float4* P4 = (const float4*)P;
  float4 s = ((const float4*)base)[i4];
  for (int c = 0; c < nc; ++c) {
    float4 v = P4[(size_t)c * n4 + i4];
    s.x += v.x; s.y += v.y; s.z += v.z; s.w += v.w;
  }
  ((float4*)Y)[i4] = s;
}

// ------- fused: h = x + sum_c P[c] (wo partials) ; hn = rmsnorm(h) -------
// grid = 8 (one per b), block = 1024; P layout [chunk nc][8][4096]
__global__ __launch_bounds__(1024) void h_norm_k(const float* __restrict__ P,
                                                 const float* __restrict__ x,
                                                 const float* __restrict__ w,
                                                 float* __restrict__ hbuf,
                                                 float* __restrict__ hn, int nc) {
  int b = blockIdx.x, tid = threadIdx.x;        // tid = float4 index in row
  const float4* P4 = (const float4*)P;
  float4 s = ((const float4*)x)[b * 1024 + tid];
  for (int c = 0; c < nc; ++c) {
    float4 v = P4[((size_t)c * 8 + b) * 1024 + tid];
    s.x += v.x; s.y += v.y; s.z += v.z; s.w += v.w;
  }
  ((float4*)hbuf)[b * 1024 + tid] = s;
  float ss = s.x * s.x + s.y * s.y + s.z * s.z + s.w * s.w;
  __shared__ float red[1024];
  red[tid] = ss; __syncthreads();
  for (int st = 512; st; st >>= 1) { if (tid < st) red[tid] += red[tid + st]; __syncthreads(); }
  float r = rsqrtf(red[0] / (float)D_ + EPS_);
  float4 wv = ((const float4*)w)[tid];
  float4 o;
  o.x = s.x * r * wv.x; o.y = s.y * r * wv.y; o.z = s.z * r * wv.z; o.w = s.w * r * wv.w;
  ((float4*)hn)[b * 1024 + tid] = o;
}

// ------- FFN: gb = silu(sum P[z=0]) * (sum P[z=1]) ; P [z(2)][chunk(nc)][8][11008] -------
__global__ __launch_bounds__(256) void reduce_silu_k(const float* __restrict__ P,
                                                     float* __restrict__ gb, int nc) {
  int i4 = blockIdx.x * 256 + threadIdx.x;      // < 22016
  const float4* P4 = (const float4*)P;
  float4 a = make_float4(0.f, 0.f, 0.f, 0.f);
  float4 b = make_float4(0.f, 0.f, 0.f, 0.f);
  for (int c = 0; c < nc; ++c) {
    float4 u = P4[(size_t)c * 22016 + i4];
    float4 v = P4[(size_t)(nc + c) * 22016 + i4];
    a.x += u.x; a.y += u.y; a.z += u.z; a.w += u.w;
    b.x += v.x; b.y += v.y; b.z += v.z; b.w += v.w;
  }
  float4 o;
  o.x = (a.x / (1.f + __expf(-a.x))) * b.x;
  o.y = (a.y / (1.f + __expf(-a.y))) * b.y;
  o.z = (a.z / (1.f + __expf(-a.z))) * b.z;
  o.w = (a.w / (1.f + __expf(-a.w))) * b.w;
  ((float4*)gb)[i4] = o;
}

// ---------------- attention pass 1: barrier-free online flash-decode ----------------
// One (b,h,chunk-of-256) per block; each half-wave owns 64 interleaved positions with
// online softmax. Per-wave partial: part[(idx*4+wave)*PSTRIDE] = [m, l, pad..., o[128]@+32].
__global__ __launch_bounds__(256) void attn_partial(
    const float* __restrict__ qp,   // rows 0..7 = q, post-rope
    const float* __restrict__ ck,
    const float* __restrict__ cv,
    float* __restrict__ part) {
  int idx = blockIdx.x;
  int c = idx & 7, bh = idx >> 3;
  int h = bh & 31, b = bh >> 5;
  int tid = threadIdx.x, wave = tid >> 6, lane = tid & 63;
  int half = lane >> 5, l32 = lane & 31;
  int t0 = c * 256 + wave * 64;
  const float4 qv = *(const float4*)&qp[(size_t)b * D_ + h * HD_ + 4 * l32];
  const size_t kvbase = ((size_t)b * MAXSEQ_) * (H_ * HD_) + (size_t)h * HD_ + 4 * l32;
  float m = -INFINITY, l = 0.f;
  float4 o = make_float4(0.f, 0.f, 0.f, 0.f);
#pragma unroll 4
  for (int i = 0; i < 32; ++i) {
    int t = t0 + 2 * i + half;
    size_t off = kvbase + (size_t)t * (H_ * HD_);
    float4 kv = *(const float4*)&ck[off];
    float s = qv.x * kv.x + qv.y * kv.y + qv.z * kv.z + qv.w * kv.w;
    s += __shfl_xor(s, 16); s += __shfl_xor(s, 8);
    s += __shfl_xor(s, 4);  s += __shfl_xor(s, 2); s += __shfl_xor(s, 1);
    s *= SCALE_;
    if (t == MAXSEQ_ - 1) s = -1e30f;     // new token folded in combine
    float mn = fmaxf(m, s);
    float r = __expf(m - mn), p = __expf(s - mn);
    float4 vv = *(const float4*)&cv[off];
    o.x = o.x * r + p * vv.x; o.y = o.y * r + p * vv.y;
    o.z = o.z * r + p * vv.z; o.w = o.w * r + p * vv.w;
    l = l * r + p; m = mn;
  }
  // merge the two 32-lane halves
  float mo = __shfl_xor(m, 32);
  float M = fmaxf(m, mo);
  float e = __expf(m - M);
  o.x *= e; o.y *= e; o.z *= e; o.w *= e; l *= e;
  o.x += __shfl_xor(o.x, 32); o.y += __shfl_xor(o.y, 32);
  o.z += __shfl_xor(o.z, 32); o.w += __shfl_xor(o.w, 32);
  l += __shfl_xor(l, 32);
  float* po = &part[((size_t)idx * 4 + wave) * PSTRIDE];
  if (lane == 0) { po[0] = M; po[1] = l; }
  if (half == 0) *(float4*)&po[32 + 4 * l32] = o;
}

// --- attention pass 2: combine 32 partials + fold new token + adapter attention + gate ---
__global__ __launch_bounds__(128) void attn_combine(
    const float* __restrict__ part,
    const float* __restrict__ qp,
    const float* __restrict__ kvk,  // rows 0..7 = new k (roped), rows 8..17 = ak
    const float* __restrict__ kvv,  // rows 0..7 = new v,         rows 8..17 = av
    const float* __restrict__ gate,
    float* __restrict__ attn) {
  int bh = blockIdx.x;
  int h = bh & 31, b = bh >> 5;
  int tid = threadIdx.x;            // = d in [0,128)
  const float* pb = &part[(size_t)bh * 32 * PSTRIDE];
  __shared__ float sm[32], sl[32];
  if (tid < 32) { sm[tid] = pb[tid * PSTRIDE]; sl[tid] = pb[tid * PSTRIDE + 1]; }
  __syncthreads();
  float M = -INFINITY;
  for (int c = 0; c < 32; ++c) M = fmaxf(M, sm[c]);
  float L = 0.f, O = 0.f;
  for (int c = 0; c < 32; ++c) {
    float e = __expf(sm[c] - M);
    L += e * sl[c];
    O += e * pb[c * PSTRIDE + 32 + tid];
  }
  size_t qi = (size_t)b * D_ + h * HD_ + tid;
  float qd = qp[qi];
  __shared__ float red[128];
  __shared__ float sa[10];
  red[tid] = qd * kvk[qi]; __syncthreads();
  for (int s = 64; s; s >>= 1) { if (tid < s) red[tid] += red[tid + s]; __syncthreads(); }
  float s_new = red[0] * SCALE_;
  __syncthreads();
  float M2 = fmaxf(M, s_new);
  float eM = __expf(M - M2), eN = __expf(s_new - M2);
  L = L * eM + eN;
  O = O * eM + eN * kvv[qi];
  float main_out = O / L;
  for (int j = 0; j < 10; ++j) {
    float prod = qd * kvk[(size_t)(8 + j) * D_ + h * HD_ + tid];
    red[tid] = prod; __syncthreads();
    for (int s = 64; s; s >>= 1) { if (tid < s) red[tid] += red[tid + s]; __syncthreads(); }
    if (tid == 0) sa[j] = red[0] * SCALE_;
    __syncthreads();
  }
  float ma = -INFINITY;
  for (int j = 0; j < 10; ++j) ma = fmaxf(ma, sa[j]);
  float la = 0.f, pj[10];
  for (int j = 0; j < 10; ++j) { pj[j] = __expf(sa[j] - ma); la += pj[j]; }
  float ao = 0.f;
  for (int j = 0; j < 10; ++j) ao += pj[j] * kvv[(size_t)(8 + j) * D_ + h * HD_ + tid];
  ao /= la;
  float g = tanhf(gate[h]);
  attn[qi] = main_out + g * ao;
}

extern "C" void kernel_launch(void* const* d_in, const int* in_sizes, int n_in,
                              void* d_out, int out_size, void* d_ws, size_t ws_size,
                              hipStream_t stream) {
  (void)in_sizes; (void)n_in; (void)out_size;
  const float* x       = (const float*)d_in[0];
  const float* adapter = (const float*)d_in[1];
  const float* ck      = (const float*)d_in[2];
  const float* cv      = (const float*)d_in[3];
  const float* fc      = (const float*)d_in[4];
  const float* fs      = (const float*)d_in[5];
  const float* wq      = (const float*)d_in[6];
  const float* wk      = (const float*)d_in[7];
  const float* wv      = (const float*)d_in[8];
  const float* wo      = (const float*)d_in[9];
  const float* gate    = (const float*)d_in[10];
  const float* anw     = (const float*)d_in[11];
  const float* fnw     = (const float*)d_in[12];
  const float* w1      = (const float*)d_in[13];
  const float* w2      = (const float*)d_in[14];
  const float* w3      = (const float*)d_in[15];
  float* out = (float*)d_out;

  float* ws      = (float*)d_ws;
  float* xa      = ws;                     // 18*4096
  float* qp      = xa + 18 * D_;           // rows 0..7 = q (roped)
  float* kp      = qp + 18 * D_;           // rows 0..7 = new k (roped), 8..17 = ak
  float* vp      = kp + 18 * D_;           // rows 0..7 = new v, 8..17 = av
  float* attn    = vp + 18 * D_;           // 8*4096
  float* hbuf    = attn + 8 * D_;          // 8*4096
  float* hn      = hbuf + 8 * D_;          // 8*4096
  float* gb      = hn + 8 * D_;            // 8*11008
  float* scratch = gb + 8 * FF_;
  // fixed buffers = 1,359,872 floats (5.4 MB).
  // wide path scratch max = QKV partials 3*32*18*4096 = 7,077,888 floats (28.3 MB) -> ~34 MB total.
  bool wide = ws_size >= (size_t)40 * 1024 * 1024;

  // 1) xa = [rmsnorm(x); adapter]
  norm_adapter_k<<<18, 256, 0, stream>>>(x, anw, adapter, xa);

  if (wide) {
    // 2) QKV: CHUNK 128, 32 chunks, 1536 blocks (~6/CU)
    gemv_rs<18, 5, 128, 8><<<dim3(16, 32, 3), 256, 0, stream>>>(xa, wq, wk, wv, scratch, D_, D_);
    reduce3_rope_k<<<dim3(72, 1, 3), 256, 0, stream>>>(scratch, fc, fs, qp, kp, vp, 32);
  } else {
    gemv_rs<18, 5, 256, 16><<<dim3(16, 16, 3), 256, 0, stream>>>(xa, wq, wk, wv, scratch, D_, D_);
    reduce3_rope_k<<<dim3(72, 1, 3), 256, 0, stream>>>(scratch, fc, fs, qp, kp, vp, 16);
  }
  // 3) barrier-free flash-decode (new token folded in combine)
  attn_partial<<<2048, 256, 0, stream>>>(qp, ck, cv, scratch);
  attn_combine<<<256, 128, 0, stream>>>(scratch, qp, kp, vp, gate, attn);
  // 4) h = x + attn @ wo ; hn = rmsnorm(h)   (fused reduce+norm)
  if (wide) {
    gemv_rs<8, 2, 64, 8><<<dim3(16, 64, 1), 256, 0, stream>>>(attn, wo, wo, wo, scratch, D_, D_);
    h_norm_k<<<8, 1024, 0, stream>>>(scratch, x, fnw, hbuf, hn, 64);
  } else {
    gemv_rs<8, 2, 128, 16><<<dim3(16, 32, 1), 256, 0, stream>>>(attn, wo, wo, wo, scratch, D_, D_);
    h_norm_k<<<8, 1024, 0, stream>>>(scratch, x, fnw, hbuf, hn, 32);
  }
  // 5) FFN up+gate -> fused reduce+silu
  if (wide) {
    gemv_rs<8, 2, 128, 8><<<dim3(43, 32, 2), 256, 0, stream>>>(hn, w1, w3, w3, scratch, FF_, D_);
    reduce_silu_k<<<86, 256, 0, stream>>>(scratch, gb, 32);
  } else {
    gemv_rs<8, 2, 512, 16><<<dim3(43, 8, 2), 256, 0, stream>>>(hn, w1, w3, w3, scratch, FF_, D_);
    reduce_silu_k<<<86, 256, 0, stream>>>(scratch, gb, 8);
  }
  // 6) out = h + gb @ w2
  if (wide) {
    gemv_rs<8, 2, 128, 8><<<dim3(16, 86, 1), 256, 0, stream>>>(gb, w2, w2, w2, scratch, D_, FF_);
    reduceB_k<<<32, 256, 0, stream>>>(scratch, hbuf, out, 8192, 86);
  } else {
    gemv_rs<8, 2, 344, 8><<<dim3(16, 32, 1), 256, 0, stream>>>(gb, w2, w2, w2, scratch, D_, FF_);
    reduceB_k<<<32, 256, 0, stream>>>(scratch, hbuf, out, 8192, 32);
  }
}

// Round 11
// 394.821 us; speedup vs baseline: 4.4251x; 1.1461x over previous
//
#include <hip/hip_runtime.h>
#include <cmath>

#define D_ 4096
#define H_ 32
#define HD_ 128
#define B_ 8
#define MAXSEQ_ 2048
#define AL_ 10
#define FF_ 11008
#define SCALE_ 0.08838834764831845f   // 1/sqrt(128)
#define EPS_ 1e-5f
#define PSTRIDE 160                   // attn partial record stride (floats); o[] at +32 (64B aligned)

// ---------- fused: rmsnorm(x) -> xa rows 0..7 ; adapter copy -> xa rows 8..17 ----------
__global__ __launch_bounds__(256) void norm_adapter_k(const float* __restrict__ x,
                                                      const float* __restrict__ w,
                                                      const float* __restrict__ adapter,
                                                      float* __restrict__ xa) {
  int b = blockIdx.x, tid = threadIdx.x;
  if (b < 8) {
    const float* xr = x + (size_t)b * D_;
    float ss = 0.f;
    for (int i = tid; i < D_; i += 256) { float v = xr[i]; ss += v * v; }
    __shared__ float red[256];
    red[tid] = ss; __syncthreads();
    for (int s = 128; s; s >>= 1) { if (tid < s) red[tid] += red[tid + s]; __syncthreads(); }
    float r = rsqrtf(red[0] / (float)D_ + EPS_);
    float* o = xa + (size_t)b * D_;
    for (int i = tid; i < D_; i += 256) o[i] = xr[i] * r * w[i];
  } else {
    int r = b - 8;
    const float4* src = (const float4*)(adapter + (size_t)r * D_);
    float4* dst = (float4*)(xa + (size_t)(8 + r) * D_);
    for (int i = tid; i < D_ / 4; i += 256) dst[i] = src[i];
  }
}

// ------------- row-split split-K GEMV: 4 waves/block, each wave owns <=NR rows -------------
template<int NR, int ROWS, int CHUNK, int UNROLL>
__device__ __forceinline__ void gemv_core(
    const float4* __restrict__ W4, const float (*xs)[ROWS],
    int i0, int N4, int j4, int r0, float* __restrict__ P, size_t pb, int N) {
  float4 acc[NR];
#pragma unroll
  for (int r = 0; r < NR; ++r) acc[r] = make_float4(0.f, 0.f, 0.f, 0.f);
  for (int iu = 0; iu < CHUNK; iu += UNROLL) {
    float4 w[UNROLL];
#pragma unroll
    for (int u = 0; u < UNROLL; ++u)
      w[u] = W4[(size_t)(i0 + iu + u) * N4 + j4];
#pragma unroll
    for (int u = 0; u < UNROLL; ++u) {
#pragma unroll
      for (int r = 0; r < NR; ++r) {
        float xv = xs[iu + u][r0 + r];
        acc[r].x += xv * w[u].x; acc[r].y += xv * w[u].y;
        acc[r].z += xv * w[u].z; acc[r].w += xv * w[u].w;
      }
    }
  }
#pragma unroll
  for (int r = 0; r < NR; ++r)
    *(float4*)&P[(pb + r) * (size_t)N + (size_t)4 * j4] = acc[r];
}

// grid = (N4/64, K/CHUNK, nmat); block = 256 (4 waves).
template<int ROWS, int RPG, int CHUNK, int UNROLL>
__global__ __launch_bounds__(256, 1) void gemv_rs(
    const float* __restrict__ X,
    const float* __restrict__ Wa, const float* __restrict__ Wb, const float* __restrict__ Wc,
    float* __restrict__ P, int N, int K) {
  const float* W = (blockIdx.z == 0) ? Wa : (blockIdx.z == 1) ? Wb : Wc;
  __shared__ float xs[CHUNK][ROWS];
  int tid = threadIdx.x;
  int i0 = blockIdx.y * CHUNK;
  for (int idx = tid; idx < ROWS * CHUNK; idx += 256) {
    int r = idx / CHUNK, ii = idx - r * CHUNK;
    xs[ii][r] = X[(size_t)r * K + i0 + ii];
  }
  __syncthreads();
  int wave = tid >> 6, lane = tid & 63;
  int r0 = wave * RPG;
  int N4 = N >> 2;
  int j4 = blockIdx.x * 64 + lane;
  const float4* W4 = (const float4*)W;
  size_t pb = ((size_t)blockIdx.z * gridDim.y + blockIdx.y) * ROWS + r0;
  constexpr int LAST = ROWS - 3 * RPG;
  if (r0 + RPG <= ROWS)
    gemv_core<RPG, ROWS, CHUNK, UNROLL>(W4, xs, i0, N4, j4, r0, P, pb, N);
  else if (LAST > 0)
    gemv_core<(LAST > 0 ? LAST : 1), ROWS, CHUNK, UNROLL>(W4, xs, i0, N4, j4, r0, P, pb, N);
}

// ------- QKV reduction over 16 chunks + fused RoPE on q,k rows 0..7 -------
// P: [z(3)][chunk(16)][row(18)][4096]
__global__ __launch_bounds__(256) void reduce3_rope_k(
    const float* __restrict__ P, const float* __restrict__ fc, const float* __restrict__ fs,
    float* __restrict__ Ya, float* __restrict__ Yb, float* __restrict__ Yc) {
  int z = blockIdx.z;
  int i4 = blockIdx.x * 256 + threadIdx.x;      // 18432 float4 per z
  const float4* P4 = (const float4*)P;
  size_t base = (size_t)z * 16 * 18432 + i4;
  float4 s = make_float4(0.f, 0.f, 0.f, 0.f);
#pragma unroll
  for (int c = 0; c < 16; ++c) {
    float4 v = P4[base + (size_t)c * 18432];
    s.x += v.x; s.y += v.y; s.z += v.z; s.w += v.w;
  }
  int row = i4 >> 10;
  if (z < 2 && row < 8) {
    int c0 = (i4 & 1023) << 2;
    int p0 = (c0 & 127) >> 1;
    float ca = fc[p0], sa = fs[p0], cb = fc[p0 + 1], sb = fs[p0 + 1];
    float4 r;
    r.x = s.x * ca - s.y * sa; r.y = s.x * sa + s.y * ca;
    r.z = s.z * cb - s.w * sb; r.w = s.z * sb + s.w * cb;
    s = r;
  }
  float4* Y = (float4*)(z == 0 ? Ya : z == 1 ? Yb : Yc);
  Y[i4] = s;
}

// ------- reduction with residual base: Y = base + sum_c P[c] -------
__global__ __launch_bounds__(256) void reduceB_k(const float* __restrict__ P,
                                                 const float* __restrict__ base,
                                                 float* __restrict__ Y, int n4, int nc) {
  int i4 = blockIdx.x * 256 + threadIdx.x;
  if (i4 >= n4) return;
  const float4* P4 = (const float4*)P;
  float4 s = ((const float4*)base)[i4];
  for (int c = 0; c < nc; ++c) {
    float4 v = P4[(size_t)c * n4 + i4];
    s.x += v.x; s.y += v.y; s.z += v.z; s.w += v.w;
  }
  ((float4*)Y)[i4] = s;
}

// ------- fused: h = x + sum_c P[c] (wo partials) ; hn = rmsnorm(h) -------
// grid = 8 (one per b), block = 1024; P layout [chunk nc][8][4096]
__global__ __launch_bounds__(1024) void h_norm_k(const float* __restrict__ P,
                                                 const float* __restrict__ x,
                                                 const float* __restrict__ w,
                                                 float* __restrict__ hbuf,
                                                 float* __restrict__ hn, int nc) {
  int b = blockIdx.x, tid = threadIdx.x;        // tid = float4 index in row
  const float4* P4 = (const float4*)P;
  float4 s = ((const float4*)x)[b * 1024 + tid];
  for (int c = 0; c < nc; ++c) {
    float4 v = P4[((size_t)c * 8 + b) * 1024 + tid];
    s.x += v.x; s.y += v.y; s.z += v.z; s.w += v.w;
  }
  ((float4*)hbuf)[b * 1024 + tid] = s;
  float ss = s.x * s.x + s.y * s.y + s.z * s.z + s.w * s.w;
  __shared__ float red[1024];
  red[tid] = ss; __syncthreads();
  for (int st = 512; st; st >>= 1) { if (tid < st) red[tid] += red[tid + st]; __syncthreads(); }
  float r = rsqrtf(red[0] / (float)D_ + EPS_);
  float4 wv = ((const float4*)w)[tid];
  float4 o;
  o.x = s.x * r * wv.x; o.y = s.y * r * wv.y; o.z = s.z * r * wv.z; o.w = s.w * r * wv.w;
  ((float4*)hn)[b * 1024 + tid] = o;
}

// ------- FFN: gb = silu(sum P[z=0]) * (sum P[z=1]) ; P [z(2)][chunk(8)][8][11008] -------
__global__ __launch_bounds__(256) void reduce_silu_k(const float* __restrict__ P,
                                                     float* __restrict__ gb) {
  int i4 = blockIdx.x * 256 + threadIdx.x;      // < 22016
  const float4* P4 = (const float4*)P;
  float4 a = make_float4(0.f, 0.f, 0.f, 0.f);
  float4 b = make_float4(0.f, 0.f, 0.f, 0.f);
#pragma unroll
  for (int c = 0; c < 8; ++c) {
    float4 u = P4[(size_t)c * 22016 + i4];
    float4 v = P4[(size_t)(8 + c) * 22016 + i4];
    a.x += u.x; a.y += u.y; a.z += u.z; a.w += u.w;
    b.x += v.x; b.y += v.y; b.z += v.z; b.w += v.w;
  }
  float4 o;
  o.x = (a.x / (1.f + __expf(-a.x))) * b.x;
  o.y = (a.y / (1.f + __expf(-a.y))) * b.y;
  o.z = (a.z / (1.f + __expf(-a.z))) * b.z;
  o.w = (a.w / (1.f + __expf(-a.w))) * b.w;
  ((float4*)gb)[i4] = o;
}

// ---------------- attention pass 1: barrier-free online flash-decode ----------------
// One (b,h,chunk-of-256) per block; each half-wave owns 64 interleaved positions with
// online softmax. Per-wave partial: part[(idx*4+wave)*PSTRIDE] = [m, l, pad..., o[128]@+32].
__global__ __launch_bounds__(256) void attn_partial(
    const float* __restrict__ qp,   // rows 0..7 = q, post-rope
    const float* __restrict__ ck,
    const float* __restrict__ cv,
    float* __restrict__ part) {
  int idx = blockIdx.x;
  int c = idx & 7, bh = idx >> 3;
  int h = bh & 31, b = bh >> 5;
  int tid = threadIdx.x, wave = tid >> 6, lane = tid & 63;
  int half = lane >> 5, l32 = lane & 31;
  int t0 = c * 256 + wave * 64;
  const float4 qv = *(const float4*)&qp[(size_t)b * D_ + h * HD_ + 4 * l32];
  const size_t kvbase = ((size_t)b * MAXSEQ_) * (H_ * HD_) + (size_t)h * HD_ + 4 * l32;
  float m = -INFINITY, l = 0.f;
  float4 o = make_float4(0.f, 0.f, 0.f, 0.f);
#pragma unroll 4
  for (int i = 0; i < 32; ++i) {
    int t = t0 + 2 * i + half;
    size_t off = kvbase + (size_t)t * (H_ * HD_);
    float4 kv = *(const float4*)&ck[off];
    float s = qv.x * kv.x + qv.y * kv.y + qv.z * kv.z + qv.w * kv.w;
    s += __shfl_xor(s, 16); s += __shfl_xor(s, 8);
    s += __shfl_xor(s, 4);  s += __shfl_xor(s, 2); s += __shfl_xor(s, 1);
    s *= SCALE_;
    if (t == MAXSEQ_ - 1) s = -1e30f;     // new token folded in combine
    float mn = fmaxf(m, s);
    float r = __expf(m - mn), p = __expf(s - mn);
    float4 vv = *(const float4*)&cv[off];
    o.x = o.x * r + p * vv.x; o.y = o.y * r + p * vv.y;
    o.z = o.z * r + p * vv.z; o.w = o.w * r + p * vv.w;
    l = l * r + p; m = mn;
  }
  // merge the two 32-lane halves
  float mo = __shfl_xor(m, 32);
  float M = fmaxf(m, mo);
  float e = __expf(m - M);
  o.x *= e; o.y *= e; o.z *= e; o.w *= e; l *= e;
  o.x += __shfl_xor(o.x, 32); o.y += __shfl_xor(o.y, 32);
  o.z += __shfl_xor(o.z, 32); o.w += __shfl_xor(o.w, 32);
  l += __shfl_xor(l, 32);
  float* po = &part[((size_t)idx * 4 + wave) * PSTRIDE];
  if (lane == 0) { po[0] = M; po[1] = l; }
  if (half == 0) *(float4*)&po[32 + 4 * l32] = o;
}

// --- attention pass 2 (shuffle-based): combine 32 partials + new token + adapter + gate ---
__global__ __launch_bounds__(128) void attn_combine(
    const float* __restrict__ part,
    const float* __restrict__ qp,
    const float* __restrict__ kvk,  // rows 0..7 = new k (roped), rows 8..17 = ak
    const float* __restrict__ kvv,  // rows 0..7 = new v,         rows 8..17 = av
    const float* __restrict__ gate,
    float* __restrict__ attn) {
  int bh = blockIdx.x;
  int h = bh & 31, b = bh >> 5;
  int tid = threadIdx.x;            // = d in [0,128)
  int wave = tid >> 6, lane = tid & 63;
  const float* pb = &part[(size_t)bh * 32 * PSTRIDE];
  __shared__ float sm[32], sl[32];
  __shared__ float s2[2][12];
  if (tid < 32) { sm[tid] = pb[tid * PSTRIDE]; sl[tid] = pb[tid * PSTRIDE + 1]; }
  __syncthreads();
  float M = -INFINITY;
  for (int c = 0; c < 32; ++c) M = fmaxf(M, sm[c]);
  float L = 0.f, O = 0.f;
#pragma unroll 4
  for (int c = 0; c < 32; ++c) {
    float e = __expf(sm[c] - M);
    L += e * sl[c];
    O += e * pb[c * PSTRIDE + 32 + tid];
  }
  // shuffle-based scores: new token (idx 10) + 10 adapter keys
  size_t qi = (size_t)b * D_ + h * HD_ + tid;
  float qd = qp[qi];
  {
    float pr = qd * kvk[qi];
    pr += __shfl_xor(pr, 32); pr += __shfl_xor(pr, 16); pr += __shfl_xor(pr, 8);
    pr += __shfl_xor(pr, 4);  pr += __shfl_xor(pr, 2);  pr += __shfl_xor(pr, 1);
    if (lane == 0) s2[wave][10] = pr;
  }
  for (int j = 0; j < 10; ++j) {
    float pr = qd * kvk[(size_t)(8 + j) * D_ + h * HD_ + tid];
    pr += __shfl_xor(pr, 32); pr += __shfl_xor(pr, 16); pr += __shfl_xor(pr, 8);
    pr += __shfl_xor(pr, 4);  pr += __shfl_xor(pr, 2);  pr += __shfl_xor(pr, 1);
    if (lane == 0) s2[wave][j] = pr;
  }
  __syncthreads();
  float s_new = (s2[0][10] + s2[1][10]) * SCALE_;
  float M2 = fmaxf(M, s_new);
  float eM = __expf(M - M2), eN = __expf(s_new - M2);
  L = L * eM + eN;
  O = O * eM + eN * kvv[qi];
  float main_out = O / L;
  float ma = -INFINITY, sa[10];
  for (int j = 0; j < 10; ++j) { sa[j] = (s2[0][j] + s2[1][j]) * SCALE_; ma = fmaxf(ma, sa[j]); }
  float la = 0.f, pj[10];
  for (int j = 0; j < 10; ++j) { pj[j] = __expf(sa[j] - ma); la += pj[j]; }
  float ao = 0.f;
  for (int j = 0; j < 10; ++j) ao += pj[j] * kvv[(size_t)(8 + j) * D_ + h * HD_ + tid];
  ao /= la;
  float g = tanhf(gate[h]);
  attn[qi] = main_out + g * ao;
}

extern "C" void kernel_launch(void* const* d_in, const int* in_sizes, int n_in,
                              void* d_out, int out_size, void* d_ws, size_t ws_size,
                              hipStream_t stream) {
  (void)in_sizes; (void)n_in; (void)out_size; (void)ws_size;
  const float* x       = (const float*)d_in[0];
  const float* adapter = (const float*)d_in[1];
  const float* ck      = (const float*)d_in[2];
  const float* cv      = (const float*)d_in[3];
  const float* fc      = (const float*)d_in[4];
  const float* fs      = (const float*)d_in[5];
  const float* wq      = (const float*)d_in[6];
  const float* wk      = (const float*)d_in[7];
  const float* wv      = (const float*)d_in[8];
  const float* wo      = (const float*)d_in[9];
  const float* gate    = (const float*)d_in[10];
  const float* anw     = (const float*)d_in[11];
  const float* fnw     = (const float*)d_in[12];
  const float* w1      = (const float*)d_in[13];
  const float* w2      = (const float*)d_in[14];
  const float* w3      = (const float*)d_in[15];
  float* out = (float*)d_out;

  float* ws      = (float*)d_ws;
  float* xa      = ws;                     // 18*4096
  float* qp      = xa + 18 * D_;           // rows 0..7 = q (roped)
  float* kp      = qp + 18 * D_;           // rows 0..7 = new k (roped), 8..17 = ak
  float* vp      = kp + 18 * D_;           // rows 0..7 = new v, 8..17 = av
  float* attn    = vp + 18 * D_;           // 8*4096
  float* hbuf    = attn + 8 * D_;          // 8*4096
  float* hn      = hbuf + 8 * D_;          // 8*4096
  float* gb      = hn + 8 * D_;            // 8*11008
  float* scratch = gb + 8 * FF_;           // max phase: QKV partials 3*16*18*4096 = 13.5 MB

  // 1) xa = [rmsnorm(x); adapter]
  norm_adapter_k<<<18, 256, 0, stream>>>(x, anw, adapter, xa);
  // 2) QKV projections -> partials -> reduce (+rope q,k rows 0..7)
  gemv_rs<18, 5, 256, 16><<<dim3(16, 16, 3), 256, 0, stream>>>(xa, wq, wk, wv, scratch, D_, D_);
  reduce3_rope_k<<<dim3(72, 1, 3), 256, 0, stream>>>(scratch, fc, fs, qp, kp, vp);
  // 3) barrier-free flash-decode (new token folded in combine)
  attn_partial<<<2048, 256, 0, stream>>>(qp, ck, cv, scratch);
  attn_combine<<<256, 128, 0, stream>>>(scratch, qp, kp, vp, gate, attn);
  // 4) h = x + attn @ wo ; hn = rmsnorm(h)  (fused reduce+norm)
  gemv_rs<8, 2, 128, 16><<<dim3(16, 32, 1), 256, 0, stream>>>(attn, wo, wo, wo, scratch, D_, D_);
  h_norm_k<<<8, 1024, 0, stream>>>(scratch, x, fnw, hbuf, hn, 32);
  // 5) FFN up+gate -> fused reduce+silu
  gemv_rs<8, 2, 512, 16><<<dim3(43, 8, 2), 256, 0, stream>>>(hn, w1, w3, w3, scratch, FF_, D_);
  reduce_silu_k<<<86, 256, 0, stream>>>(scratch, gb);
  // 6) out = h + gb @ w2
  gemv_rs<8, 2, 344, 8><<<dim3(16, 32, 1), 256, 0, stream>>>(gb, w2, w2, w2, scratch, D_, FF_);
  reduceB_k<<<32, 256, 0, stream>>>(scratch, hbuf, out, 8192, 32);
}